// Round 1
// baseline (1094.971 us; speedup 1.0000x reference)
//
#include <hip/hip_runtime.h>
#include <hip/hip_bf16.h>

// Problem: y[b,f,c] = sum_hw x[b,c,hw] * k[f,c,hw];  out[b, f*C + c]
// B=256, F=16, C=256, HW=1024. fp32 in/out.
//
// Memory-bound: x = 256 MiB read-once dominates (HBM floor ~46us).
// Block = (c, 64-b tile); K_c staged in LDS in 16 KiB chunks; each thread
// register-blocks 4b x 16f accumulators so LDS traffic stays at ~1 GiB.

constexpr int Bb = 256;
constexpr int Ff = 16;
constexpr int Cc = 256;
constexpr int HW = 1024;
constexpr int CHW = Cc * HW;       // elements per b of x / per f of k

constexpr int CH = 256;            // hw chunk staged in LDS (floats)
constexpr int NCHUNK = HW / CH;    // 4
constexpr int BT = 64;             // b per block
constexpr int RB = 4;              // b per thread
constexpr int THW = 16;            // hw-split ways (lanes sharing one (b-group))
constexpr int NTHREADS = (BT / RB) * THW;  // 256

__global__ __launch_bounds__(NTHREADS, 4)
void sle_kernel(const float* __restrict__ x, const float* __restrict__ k,
                float* __restrict__ out) {
    __shared__ float ldsK[Ff * CH];           // 16 KiB

    const int t    = threadIdx.x;
    const int thw  = t & (THW - 1);           // 0..15  hw split
    const int tbg  = t >> 4;                  // 0..15  b group
    const int c     = blockIdx.x & (Cc - 1);  // grid = Cc * (Bb/BT) = 1024
    const int btile = blockIdx.x >> 8;        // 0..3
    const int b0    = btile * BT + tbg * RB;

    // per-thread x base pointers (4 b's), at channel c
    const float* xp[RB];
#pragma unroll
    for (int bb = 0; bb < RB; ++bb)
        xp[bb] = x + (size_t)(b0 + bb) * CHW + (size_t)c * HW;

    float acc[RB][Ff];
#pragma unroll
    for (int bb = 0; bb < RB; ++bb)
#pragma unroll
        for (int f = 0; f < Ff; ++f) acc[bb][f] = 0.0f;

    for (int ch = 0; ch < NCHUNK; ++ch) {
        const int hw0 = ch * CH;
        __syncthreads();  // previous chunk's compute done before overwrite
        {
            // stage K[f=0..15][hw0..hw0+CH) -> ldsK : 4096 floats, 16 floats/thread
            const int fr     = t >> 4;        // 16 threads per f-row
            const int lane16 = t & 15;
            const float4* src = (const float4*)(k + (size_t)fr * CHW
                                                  + (size_t)c * HW + hw0);
            float4* dst = (float4*)(ldsK + fr * CH);
#pragma unroll
            for (int q = 0; q < 4; ++q)
                dst[lane16 + 16 * q] = src[lane16 + 16 * q];
        }
        __syncthreads();

#pragma unroll
        for (int j = 0; j < CH / 4 / THW; ++j) {   // 4 iters
            const int f4 = thw + THW * j;          // float4 index in chunk
            float4 xv[RB];
#pragma unroll
            for (int bb = 0; bb < RB; ++bb)
                xv[bb] = *(const float4*)(xp[bb] + hw0 + 4 * f4);
#pragma unroll
            for (int f = 0; f < Ff; ++f) {
                const float4 kv = *(const float4*)(ldsK + f * CH + 4 * f4);
#pragma unroll
                for (int bb = 0; bb < RB; ++bb) {
                    acc[bb][f] += xv[bb].x * kv.x + xv[bb].y * kv.y
                                + xv[bb].z * kv.z + xv[bb].w * kv.w;
                }
            }
        }
    }

    // reduce over the 16 hw-split lanes (butterfly keeps all lanes valid)
#pragma unroll
    for (int bb = 0; bb < RB; ++bb)
#pragma unroll
        for (int f = 0; f < Ff; ++f) {
            float v = acc[bb][f];
            v += __shfl_xor(v, 1);
            v += __shfl_xor(v, 2);
            v += __shfl_xor(v, 4);
            v += __shfl_xor(v, 8);
            acc[bb][f] = v;
        }

    // 64 results per b-group; each of the 16 lanes stores 4 of them
#pragma unroll
    for (int i = 0; i < 4; ++i) {
        const int vi = thw * 4 + i;       // 0..63
        const int bb = vi >> 4;
        const int f  = vi & 15;
        out[(size_t)(b0 + bb) * (Ff * Cc) + f * Cc + c] = acc[bb][f];
    }
}

extern "C" void kernel_launch(void* const* d_in, const int* in_sizes, int n_in,
                              void* d_out, int out_size, void* d_ws, size_t ws_size,
                              hipStream_t stream) {
    const float* x = (const float*)d_in[0];
    const float* k = (const float*)d_in[1];
    float* out = (float*)d_out;
    const int grid = Cc * (Bb / BT);  // 1024
    sle_kernel<<<grid, NTHREADS, 0, stream>>>(x, k, out);
}

// Round 2
// 892.607 us; speedup vs baseline: 1.2267x; 1.2267x over previous
//
#include <hip/hip_runtime.h>
#include <hip/hip_bf16.h>

// y[b,f,c] = sum_hw x[b,c,hw] * k[f,c,hw];  out[b, f*C + c]
// B=256, F=16, C=256, HW=1024, fp32.
//
// R1 post-mortem: dynamic indexing into acc[][] in the epilogue kept the
// accumulator array in SCRATCH (VGPR_Count=64, 1.8GB writes, 842us).
// R2: all acc indices static; epilogue goes through LDS instead.

constexpr int Bb = 256;
constexpr int Ff = 16;
constexpr int Cc = 256;
constexpr int HW = 1024;
constexpr int CHW = Cc * HW;

constexpr int CH = 256;            // hw chunk staged in LDS (floats)
constexpr int NCHUNK = HW / CH;    // 4
constexpr int BT = 64;             // b per block
constexpr int RB = 4;              // b per thread
constexpr int THW = 16;            // hw-split ways
constexpr int NTHREADS = (BT / RB) * THW;  // 256

__global__ __launch_bounds__(NTHREADS, 4)
void sle_kernel(const float* __restrict__ x, const float* __restrict__ k,
                float* __restrict__ out) {
    __shared__ float ldsK[Ff * CH];           // 16 KiB (reused by epilogue, needs 4 KiB)

    const int t    = threadIdx.x;
    const int thw  = t & (THW - 1);           // 0..15  hw split
    const int tbg  = t >> 4;                  // 0..15  b group
    const int c     = blockIdx.x & (Cc - 1);  // grid = Cc * (Bb/BT) = 1024
    const int btile = blockIdx.x >> 8;        // 0..3
    const int b0    = btile * BT + tbg * RB;

    float acc[RB][Ff];
#pragma unroll
    for (int bb = 0; bb < RB; ++bb)
#pragma unroll
        for (int f = 0; f < Ff; ++f) acc[bb][f] = 0.0f;

    const float* xc = x + (size_t)c * HW;     // x[., c, .]

    for (int ch = 0; ch < NCHUNK; ++ch) {
        const int hw0 = ch * CH;
        __syncthreads();  // previous chunk's compute done before overwrite
        {
            // stage K[f][hw0..hw0+CH) -> ldsK : 4096 floats, 16 float4/row
            const int fr     = t >> 4;
            const int lane16 = t & 15;
            const float4* src = (const float4*)(k + (size_t)fr * CHW
                                                  + (size_t)c * HW + hw0);
            float4* dst = (float4*)(ldsK + fr * CH);
#pragma unroll
            for (int q = 0; q < 4; ++q)
                dst[lane16 + 16 * q] = src[lane16 + 16 * q];
        }
        __syncthreads();

#pragma unroll
        for (int j = 0; j < CH / 4 / THW; ++j) {   // 4 iters
            const int f4  = thw + THW * j;         // float4 index in chunk
            const int off = hw0 + 4 * f4;
            float4 xv[RB];
#pragma unroll
            for (int bb = 0; bb < RB; ++bb)
                xv[bb] = *(const float4*)(xc + (size_t)(b0 + bb) * CHW + off);
#pragma unroll
            for (int f = 0; f < Ff; ++f) {
                const float4 kv = *(const float4*)(ldsK + f * CH + 4 * f4);
#pragma unroll
                for (int bb = 0; bb < RB; ++bb) {
                    acc[bb][f] += xv[bb].x * kv.x + xv[bb].y * kv.y
                                + xv[bb].z * kv.z + xv[bb].w * kv.w;
                }
            }
        }
    }

    // butterfly-reduce over the 16 hw-split lanes (all indices static)
#pragma unroll
    for (int bb = 0; bb < RB; ++bb)
#pragma unroll
        for (int f = 0; f < Ff; ++f) {
            float v = acc[bb][f];
            v += __shfl_xor(v, 1);
            v += __shfl_xor(v, 2);
            v += __shfl_xor(v, 4);
            v += __shfl_xor(v, 8);
            acc[bb][f] = v;
        }

    __syncthreads();  // all waves done reading ldsK before epilogue reuse
    if (thw == 0) {
#pragma unroll
        for (int bb = 0; bb < RB; ++bb)
#pragma unroll
            for (int f = 0; f < Ff; ++f)
                ldsK[(tbg * RB + bb) * Ff + f] = acc[bb][f];  // static acc idx
    }
    __syncthreads();

    // 1024 results per block; 4 dword stores per thread (LDS dyn-idx is fine)
#pragma unroll
    for (int i = 0; i < 4; ++i) {
        const int idx = t + NTHREADS * i;     // 0..1023
        const int bl  = idx >> 4;             // local b
        const int f   = idx & 15;
        out[(size_t)(btile * BT + bl) * (Ff * Cc) + f * Cc + c] = ldsK[idx];
    }
}

extern "C" void kernel_launch(void* const* d_in, const int* in_sizes, int n_in,
                              void* d_out, int out_size, void* d_ws, size_t ws_size,
                              hipStream_t stream) {
    const float* x = (const float*)d_in[0];
    const float* k = (const float*)d_in[1];
    float* out = (float*)d_out;
    const int grid = Cc * (Bb / BT);  // 1024
    sle_kernel<<<grid, NTHREADS, 0, stream>>>(x, k, out);
}

// Round 3
// 581.772 us; speedup vs baseline: 1.8821x; 1.5343x over previous
//
#include <hip/hip_runtime.h>
#include <hip/hip_bf16.h>

// y[b,f,c] = sum_hw x[b,c,hw] * k[f,c,hw];  out[b, f*C + c]
// B=256, F=16, C=256, HW=1024, fp32.
//
// R1/R2 post-mortem: local arrays (acc[4][16], xv[4]) ended up in scratch
// (VGPR_Count=64, ~1.1 GB loop scratch writes). R3: NO local arrays at all —
// accumulators are 8 named float4s (RB=2 -> 32 acc/thread, ~70 VGPR demand,
// comfortably under the launch_bounds(256,4) cap of 128).

constexpr int Bb = 256;
constexpr int Ff = 16;
constexpr int Cc = 256;
constexpr int HW = 1024;
constexpr int CHW = Cc * HW;

constexpr int CH = 256;            // hw floats staged in LDS per chunk
constexpr int NCHUNK = HW / CH;    // 4
constexpr int BT = 32;             // b per block
constexpr int RB = 2;              // b per thread
constexpr int NTHREADS = (BT / RB) * 16;   // 256

__device__ __forceinline__ float dot4(float4 a, float4 b) {
    return a.x * b.x + a.y * b.y + a.z * b.z + a.w * b.w;
}
__device__ __forceinline__ float red16(float v) {
    v += __shfl_xor(v, 1);
    v += __shfl_xor(v, 2);
    v += __shfl_xor(v, 4);
    v += __shfl_xor(v, 8);
    return v;
}

__global__ __launch_bounds__(NTHREADS, 4)
void sle_kernel(const float* __restrict__ x, const float* __restrict__ k,
                float* __restrict__ out) {
    __shared__ float ldsK[Ff * CH];           // 16 KiB

    const int t   = threadIdx.x;
    const int thw = t & 15;                   // hw split within 16-lane group
    const int tbg = t >> 4;                   // 0..15, b group
    // c-major in the low bits of blockIdx would scatter the 16 c's of one
    // output cache line across XCDs; use btile-minor so they share an XCD L2.
    const int btile = blockIdx.x & 7;         // 0..7
    const int c     = blockIdx.x >> 3;        // 0..255
    const int b0    = btile * BT + tbg * RB;

    const float* x0 = x + (size_t)(b0 + 0) * CHW + (size_t)c * HW;
    const float* x1 = x + (size_t)(b0 + 1) * CHW + (size_t)c * HW;

    // acc[b=0..1][f] as 8 named float4 (component = f within group of 4)
    float4 a00 = {0,0,0,0}, a01 = {0,0,0,0}, a02 = {0,0,0,0}, a03 = {0,0,0,0};
    float4 a10 = {0,0,0,0}, a11 = {0,0,0,0}, a12 = {0,0,0,0}, a13 = {0,0,0,0};

    for (int ch = 0; ch < NCHUNK; ++ch) {
        const int hw0 = ch * CH;
        __syncthreads();                      // prev chunk fully consumed
        {
            // stage K[f][hw0..hw0+CH): 4096 floats, 4 float4 per thread
            const int fr = t >> 4, lane16 = t & 15;
            const float4* src = (const float4*)(k + (size_t)fr * CHW
                                                  + (size_t)c * HW + hw0);
            float4* dst = (float4*)(ldsK + fr * CH);
#pragma unroll
            for (int q = 0; q < 4; ++q)
                dst[lane16 + 16 * q] = src[lane16 + 16 * q];
        }
        __syncthreads();

#pragma unroll
        for (int j = 0; j < 4; ++j) {
            const int f4 = thw + 16 * j;      // float4 index within chunk
            const float4 xv0 = *(const float4*)(x0 + hw0 + 4 * f4);
            const float4 xv1 = *(const float4*)(x1 + hw0 + 4 * f4);

#define ACC_G(A0, A1, G) {                                              \
            const float* kp = ldsK + (4 * (G)) * CH + 4 * f4;           \
            const float4 k0 = *(const float4*)(kp);                     \
            const float4 k1 = *(const float4*)(kp + CH);                \
            const float4 k2 = *(const float4*)(kp + 2 * CH);            \
            const float4 k3 = *(const float4*)(kp + 3 * CH);            \
            A0.x += dot4(xv0, k0); A0.y += dot4(xv0, k1);               \
            A0.z += dot4(xv0, k2); A0.w += dot4(xv0, k3);               \
            A1.x += dot4(xv1, k0); A1.y += dot4(xv1, k1);               \
            A1.z += dot4(xv1, k2); A1.w += dot4(xv1, k3); }

            ACC_G(a00, a10, 0)
            ACC_G(a01, a11, 1)
            ACC_G(a02, a12, 2)
            ACC_G(a03, a13, 3)
#undef ACC_G
        }
    }

    // reduce the 16 hw-split lanes; all lanes valid (butterfly)
#define RED4(A) { A.x = red16(A.x); A.y = red16(A.y); \
                  A.z = red16(A.z); A.w = red16(A.w); }
    RED4(a00) RED4(a01) RED4(a02) RED4(a03)
    RED4(a10) RED4(a11) RED4(a12) RED4(a13)
#undef RED4

    __syncthreads();                          // done reading ldsK as K-tile
    if (thw == 0) {
        float4* row0 = (float4*)(ldsK + (tbg * RB + 0) * Ff);
        float4* row1 = (float4*)(ldsK + (tbg * RB + 1) * Ff);
        row0[0] = a00; row0[1] = a01; row0[2] = a02; row0[3] = a03;
        row1[0] = a10; row1[1] = a11; row1[2] = a12; row1[3] = a13;
    }
    __syncthreads();

    // 512 results (32 b x 16 f); 2 dword stores per thread
#pragma unroll
    for (int i = 0; i < (BT * Ff) / NTHREADS; ++i) {   // 2
        const int idx = t + NTHREADS * i;              // 0..511
        const int bl  = idx >> 4;
        const int f   = idx & 15;
        out[(size_t)(btile * BT + bl) * (Ff * Cc) + f * Cc + c] = ldsK[idx];
    }
}

extern "C" void kernel_launch(void* const* d_in, const int* in_sizes, int n_in,
                              void* d_out, int out_size, void* d_ws, size_t ws_size,
                              hipStream_t stream) {
    const float* x = (const float*)d_in[0];
    const float* k = (const float*)d_in[1];
    float* out = (float*)d_out;
    const int grid = Cc * (Bb / BT);  // 2048
    sle_kernel<<<grid, NTHREADS, 0, stream>>>(x, k, out);
}

// Round 4
// 391.169 us; speedup vs baseline: 2.7992x; 1.4873x over previous
//
#include <hip/hip_runtime.h>
#include <hip/hip_bf16.h>

// y[b,f,c] = sum_hw x[b,c,hw] * k[f,c,hw];  out[b, f*C + c]
// B=256, F=16, C=256, HW=1024, fp32.
//
// R3 post-mortem: VGPR_Count pinned at exactly 64 across three structurally
// different kernels while scratch writes scaled with accumulator count =>
// __launch_bounds__(256,4)'s waves-per-eu attribute caps the allocator at
// 64 VGPRs and the ~70-80 VGPR demand spills into the inner loop.
// R4: identical compute structure, launch_bounds occupancy hint REMOVED.

constexpr int Bb = 256;
constexpr int Ff = 16;
constexpr int Cc = 256;
constexpr int HW = 1024;
constexpr int CHW = Cc * HW;

constexpr int CH = 256;            // hw floats staged in LDS per chunk
constexpr int NCHUNK = HW / CH;    // 4
constexpr int BT = 32;             // b per block
constexpr int RB = 2;              // b per thread
constexpr int NTHREADS = (BT / RB) * 16;   // 256

__device__ __forceinline__ float dot4(float4 a, float4 b) {
    return a.x * b.x + a.y * b.y + a.z * b.z + a.w * b.w;
}
__device__ __forceinline__ float red16(float v) {
    v += __shfl_xor(v, 1);
    v += __shfl_xor(v, 2);
    v += __shfl_xor(v, 4);
    v += __shfl_xor(v, 8);
    return v;
}

__global__ __launch_bounds__(NTHREADS)   // NO waves-per-eu hint: let the
                                         // allocator take ~100 VGPRs
void sle_kernel(const float* __restrict__ x, const float* __restrict__ k,
                float* __restrict__ out) {
    __shared__ float ldsK[Ff * CH];           // 16 KiB

    const int t   = threadIdx.x;
    const int thw = t & 15;                   // hw split within 16-lane group
    const int tbg = t >> 4;                   // 0..15, b group
    const int btile = blockIdx.x & 7;         // 0..7  (same-c blocks adjacent)
    const int c     = blockIdx.x >> 3;        // 0..255
    const int b0    = btile * BT + tbg * RB;

    const float* x0 = x + (size_t)(b0 + 0) * CHW + (size_t)c * HW;
    const float* x1 = x + (size_t)(b0 + 1) * CHW + (size_t)c * HW;

    // acc[b=0..1][f] as 8 named float4 (component = f within group of 4)
    float4 a00 = {0,0,0,0}, a01 = {0,0,0,0}, a02 = {0,0,0,0}, a03 = {0,0,0,0};
    float4 a10 = {0,0,0,0}, a11 = {0,0,0,0}, a12 = {0,0,0,0}, a13 = {0,0,0,0};

    for (int ch = 0; ch < NCHUNK; ++ch) {
        const int hw0 = ch * CH;
        __syncthreads();                      // prev chunk fully consumed
        {
            // stage K[f][hw0..hw0+CH): 4096 floats, 4 float4 per thread
            const int fr = t >> 4, lane16 = t & 15;
            const float4* src = (const float4*)(k + (size_t)fr * CHW
                                                  + (size_t)c * HW + hw0);
            float4* dst = (float4*)(ldsK + fr * CH);
#pragma unroll
            for (int q = 0; q < 4; ++q)
                dst[lane16 + 16 * q] = src[lane16 + 16 * q];
        }
        __syncthreads();

#pragma unroll
        for (int j = 0; j < 4; ++j) {
            const int f4 = thw + 16 * j;      // float4 index within chunk
            const float4 xv0 = *(const float4*)(x0 + hw0 + 4 * f4);
            const float4 xv1 = *(const float4*)(x1 + hw0 + 4 * f4);

#define ACC_G(A0, A1, G) {                                              \
            const float* kp = ldsK + (4 * (G)) * CH + 4 * f4;           \
            const float4 k0 = *(const float4*)(kp);                     \
            const float4 k1 = *(const float4*)(kp + CH);                \
            const float4 k2 = *(const float4*)(kp + 2 * CH);            \
            const float4 k3 = *(const float4*)(kp + 3 * CH);            \
            A0.x += dot4(xv0, k0); A0.y += dot4(xv0, k1);               \
            A0.z += dot4(xv0, k2); A0.w += dot4(xv0, k3);               \
            A1.x += dot4(xv1, k0); A1.y += dot4(xv1, k1);               \
            A1.z += dot4(xv1, k2); A1.w += dot4(xv1, k3); }

            ACC_G(a00, a10, 0)
            ACC_G(a01, a11, 1)
            ACC_G(a02, a12, 2)
            ACC_G(a03, a13, 3)
#undef ACC_G
        }
    }

    // reduce the 16 hw-split lanes; all lanes valid (butterfly)
#define RED4(A) { A.x = red16(A.x); A.y = red16(A.y); \
                  A.z = red16(A.z); A.w = red16(A.w); }
    RED4(a00) RED4(a01) RED4(a02) RED4(a03)
    RED4(a10) RED4(a11) RED4(a12) RED4(a13)
#undef RED4

    __syncthreads();                          // done reading ldsK as K-tile
    if (thw == 0) {
        float4* row0 = (float4*)(ldsK + (tbg * RB + 0) * Ff);
        float4* row1 = (float4*)(ldsK + (tbg * RB + 1) * Ff);
        row0[0] = a00; row0[1] = a01; row0[2] = a02; row0[3] = a03;
        row1[0] = a10; row1[1] = a11; row1[2] = a12; row1[3] = a13;
    }
    __syncthreads();

    // 512 results (32 b x 16 f); 2 dword stores per thread
#pragma unroll
    for (int i = 0; i < (BT * Ff) / NTHREADS; ++i) {   // 2
        const int idx = t + NTHREADS * i;              // 0..511
        const int bl  = idx >> 4;
        const int f   = idx & 15;
        out[(size_t)(btile * BT + bl) * (Ff * Cc) + f * Cc + c] = ldsK[idx];
    }
}

extern "C" void kernel_launch(void* const* d_in, const int* in_sizes, int n_in,
                              void* d_out, int out_size, void* d_ws, size_t ws_size,
                              hipStream_t stream) {
    const float* x = (const float*)d_in[0];
    const float* k = (const float*)d_in[1];
    float* out = (float*)d_out;
    const int grid = Cc * (Bb / BT);  // 2048
    sle_kernel<<<grid, NTHREADS, 0, stream>>>(x, k, out);
}